// Round 11
// baseline (382.800 us; speedup 1.0000x reference)
//
#include <hip/hip_runtime.h>
#include <type_traits>

#define D 512
#define NNODES 1365
#define OUT_STRIDE (NNODES * D)   // 698880 floats per batch row

typedef __attribute__((ext_vector_type(4))) float f32x4;
typedef __attribute__((ext_vector_type(8))) short bf16x8;

union U4 { unsigned u[4]; bf16x8 v; };

__device__ __forceinline__ unsigned cvt_pk_bf16(float s0, float s1) {
    unsigned r;
    asm volatile("v_cvt_pk_bf16_f32 %0, %1, %2" : "=v"(r) : "v"(s0), "v"(s1));
    return r;
}

__device__ __forceinline__ void gld_lds16(const void* g, void* l) {
    __builtin_amdgcn_global_load_lds(
        (const __attribute__((address_space(1))) unsigned*)g,
        (__attribute__((address_space(3))) unsigned*)l, 16, 0, 0);
}

template<int N> __device__ __forceinline__ void waitV() {
    asm volatile("s_waitcnt vmcnt(%0)" :: "i"(N) : "memory");
}

// split-bf16 fp32 MFMA emulation: AhBh + AlBh + AhBl
__device__ __forceinline__ void mfma3(bf16x8 ah, bf16x8 al, f32x4 b0, f32x4 b1,
                                      f32x4& acc) {
    U4 bH, bL;
    float xs[8] = {b0[0],b0[1],b0[2],b0[3],b1[0],b1[1],b1[2],b1[3]};
    #pragma unroll
    for (int k = 0; k < 4; ++k) {
        unsigned hh = cvt_pk_bf16(xs[2*k], xs[2*k+1]);
        float f0 = __uint_as_float(hh << 16);
        float f1 = __uint_as_float(hh & 0xFFFF0000u);
        bL.u[k] = cvt_pk_bf16(xs[2*k] - f0, xs[2*k+1] - f1);
        bH.u[k] = hh;
    }
    acc = __builtin_amdgcn_mfma_f32_16x16x32_bf16(ah, bH.v, acc, 0,0,0);
    acc = __builtin_amdgcn_mfma_f32_16x16x32_bf16(al, bH.v, acc, 0,0,0);
    acc = __builtin_amdgcn_mfma_f32_16x16x32_bf16(ah, bL.v, acc, 0,0,0);
}

__device__ __forceinline__ void build_afrags(const float* arow, int m4,
                                             bf16x8* aH, bf16x8* aL) {
    #pragma unroll
    for (int j = 0; j < 16; ++j) {
        const float* p = arow + j * 32 + m4 * 8;
        f32x4 x0 = *(const f32x4*)p;
        f32x4 x1 = *(const f32x4*)(p + 4);
        float xs[8] = {x0[0],x0[1],x0[2],x0[3],x1[0],x1[1],x1[2],x1[3]};
        U4 h, l;
        #pragma unroll
        for (int k = 0; k < 4; ++k) {
            unsigned hh = cvt_pk_bf16(xs[2*k], xs[2*k+1]);
            float f0 = __uint_as_float(hh << 16);
            float f1 = __uint_as_float(hh & 0xFFFF0000u);
            l.u[k] = cvt_pk_bf16(xs[2*k] - f0, xs[2*k+1] - f1);
            h.u[k] = hh;
        }
        aH[j] = h.v; aL[j] = l.v;
    }
}

// ========== lvl5: GLOBAL-SWEEP work assignment ==============================
// Item = 64 consecutive W-rows (128 KB) of one node; item index runs in
// MEMORY order over all of lvl5; at step t, resident blocks 0..511 process
// items t*512..t*512+511 -> the chip's concurrent reads form ONE dense
// ~64 MB window marching linearly through W (vs 1024 scattered streams).
// pa is rebuilt per item from lvl4 outputs (8 MB, L2/L3-resident -> no HBM
// cost). Inner pipeline per wave = proven R6 4-quarter gld_lds dbuf.
__global__ __launch_bounds__(256, 2)
void sweep_kernel(const float* __restrict__ W, const float* __restrict__ bias,
                  const float* __restrict__ src, float* __restrict__ out,
                  int node_start, int T, int nblk)
{
    __shared__ float Wt[4][2][2048];   // [wave][buf][8 KB]

    const int tid  = threadIdx.x;
    const int w    = tid >> 6;
    const int lane = tid & 63;
    const int m4   = lane >> 4;
    const int c0   = lane & 15;

    int loffs[8];
    const int rr  = lane >> 5;
    const int off = (lane & 31) * 16;
    #pragma unroll
    for (int i = 0; i < 8; ++i) {
        const int r = i * 2 + rr;
        loffs[i] = r * 2048 + (off ^ ((r & 7) << 4));
    }
    const int rsw = (c0 & 7) << 4;
    const int po0 = c0 * 512 + ((m4 * 32)      ^ rsw);
    const int po1 = c0 * 512 + ((m4 * 32 + 16) ^ rsw);

    auto issue = [&](const char* g, int buf) {
        char* l = (char*)&Wt[w][buf][0];
        #pragma unroll
        for (int i = 0; i < 8; ++i)
            gld_lds16(g + loffs[i], l + i * 1024);
    };

    bf16x8 aH[16], aL[16];
    auto cq = [&](auto qc, f32x4& acc) {
        constexpr int Q = decltype(qc)::value;
        const char* tb = (const char*)&Wt[w][Q & 1][0];
        #pragma unroll
        for (int ks = 0; ks < 4; ++ks) {
            f32x4 b0 = *(const f32x4*)(tb + po0 + ks * 128);
            f32x4 b1 = *(const f32x4*)(tb + po1 + ks * 128);
            mfma3(aH[Q*4+ks], aL[Q*4+ks], b0, b1, acc);
        }
    };

    #pragma clang loop unroll(disable)
    for (int t = 0; t < T; ++t) {
        const int item    = t * nblk + blockIdx.x;
        const int node    = node_start + (item >> 3);
        const int rowbase = (item & 7) * 64 + w * 16;
        const char* gb = (const char*)W
            + (size_t)node * (D * D * 4) + (size_t)rowbase * 2048;

        // pa rebuild (parent row; L2/L3-resident). cvt_pk asm consumes the
        // loads -> compiler drains them BEFORE the issues below.
        const float* arow = src + (size_t)c0 * OUT_STRIDE
                                + (size_t)((node - 1) >> 2) * D;
        build_afrags(arow, m4, aH, aL);
        const float bv = bias[(size_t)node * D + rowbase + c0];

        issue(gb,       0);
        issue(gb + 512, 1);
        f32x4 acc = {0.f, 0.f, 0.f, 0.f};
        waitV<8>(); cq(std::integral_constant<int,0>{}, acc); issue(gb + 1024, 0);
        waitV<8>(); cq(std::integral_constant<int,1>{}, acc); issue(gb + 1536, 1);
        waitV<8>(); cq(std::integral_constant<int,2>{}, acc);
        waitV<0>(); cq(std::integral_constant<int,3>{}, acc);

        const int wcol = node * D + rowbase + c0;
        #pragma unroll
        for (int i = 0; i < 4; ++i)
            out[(size_t)(m4 * 4 + i) * OUT_STRIDE + wcol] =
                fmaxf(acc[i] + bv, 0.f);
    }
}

// ========== levels 0-4: R6 node_kernel, verbatim (proven 346 us composite) ==
template<bool RELU>
__global__ __launch_bounds__(256, 2)
void node_kernel(const float* __restrict__ W, const float* __restrict__ bias,
                 const float* __restrict__ src_base, float* __restrict__ out,
                 int node_start, int bpn, int ngroups, int src_stride)
{
    __shared__ float Wt[4][2][2048];
    __shared__ float bias_lds[512];

    const int tid  = threadIdx.x;
    const int w    = tid >> 6;
    const int lane = tid & 63;
    const int m4   = lane >> 4;
    const int c0   = lane & 15;

    const int node  = node_start + blockIdx.x / bpn;
    const int nbase = (blockIdx.x % bpn) * (64 * ngroups);
    const char* Wn  = (const char*)(W + (size_t)node * (D * D));

    for (int t = tid; t < 64 * ngroups; t += 256)
        bias_lds[t] = bias[(size_t)node * D + nbase + t];

    const float* arow = (RELU ? src_base + (size_t)((node - 1) >> 2) * D
                              : src_base) + (size_t)c0 * src_stride;
    bf16x8 aH[16], aL[16];
    build_afrags(arow, m4, aH, aL);
    __syncthreads();

    int loffs[8];
    const int rr  = lane >> 5;
    const int off = (lane & 31) * 16;
    #pragma unroll
    for (int i = 0; i < 8; ++i) {
        const int r = i * 2 + rr;
        loffs[i] = r * 2048 + (off ^ ((r & 7) << 4));
    }
    auto issue = [&](const char* gsrc, int buf) {
        char* ldst = (char*)&Wt[w][buf][0];
        #pragma unroll
        for (int i = 0; i < 8; ++i)
            gld_lds16(gsrc + loffs[i], ldst + i * 1024);
    };

    const int rsw = (c0 & 7) << 4;
    const int po0 = c0 * 512 + ((m4 * 32)      ^ rsw);
    const int po1 = c0 * 512 + ((m4 * 32 + 16) ^ rsw);

    const size_t GRP = (size_t)64 * 2048;
    const char* gcur = Wn + (size_t)(nbase + w * 16) * 2048;
    issue(gcur,       0);
    issue(gcur + 512, 1);

    float* optr = out + (size_t)node * D + nbase + w * 16 + c0;
    const float* blds = &bias_lds[w * 16 + c0];

    auto compute_q = [&](auto qc, f32x4& acc) {
        constexpr int Q = decltype(qc)::value;
        const char* tb = (const char*)&Wt[w][Q & 1][0];
        #pragma unroll
        for (int ks = 0; ks < 4; ++ks) {
            f32x4 b0 = *(const f32x4*)(tb + po0 + ks * 128);
            f32x4 b1 = *(const f32x4*)(tb + po1 + ks * 128);
            mfma3(aH[Q*4+ks], aL[Q*4+ks], b0, b1, acc);
        }
    };

    #pragma clang loop unroll(disable)
    for (int g = 0; g < ngroups; ++g) {
        const bool last = (g == ngroups - 1);
        const char* gnext = gcur + GRP;
        f32x4 acc = {0.f,0.f,0.f,0.f};

        waitV<8>();
        compute_q(std::integral_constant<int,0>{}, acc);
        issue(gcur + 1024, 0);
        waitV<8>();
        compute_q(std::integral_constant<int,1>{}, acc);
        issue(gcur + 1536, 1);
        waitV<8>();
        compute_q(std::integral_constant<int,2>{}, acc);
        if (!last) issue(gnext, 0);
        if (last) waitV<0>(); else waitV<8>();
        compute_q(std::integral_constant<int,3>{}, acc);

        const float bv = *blds;
        #pragma unroll
        for (int i = 0; i < 4; ++i) {
            float v = acc[i] + bv;
            if (RELU) v = fmaxf(v, 0.f);
            optr[(size_t)(m4 * 4 + i) * OUT_STRIDE] = v;
        }
        if (!last) issue(gnext + 512, 1);

        gcur = gnext; optr += 64; blds += 64;
    }
}

extern "C" void kernel_launch(void* const* d_in, const int* in_sizes, int n_in,
                              void* d_out, int out_size, void* d_ws, size_t ws_size,
                              hipStream_t stream) {
    const float* inputs = (const float*)d_in[0];   // (16, 512)
    const float* W      = (const float*)d_in[1];   // (1365, 512, 512)
    const float* bias   = (const float*)d_in[2];   // (1365, 512)
    float* out          = (float*)d_out;           // (16, 1365*512)

    node_kernel<false><<<   8, 256, 0, stream>>>(W, bias, inputs, out,   0, 8, 1, D);
    node_kernel<true ><<<  32, 256, 0, stream>>>(W, bias, out,    out,   1, 8, 1, OUT_STRIDE);
    node_kernel<true ><<< 128, 256, 0, stream>>>(W, bias, out,    out,   5, 8, 1, OUT_STRIDE);
    node_kernel<true ><<< 512, 256, 0, stream>>>(W, bias, out,    out,  21, 8, 1, OUT_STRIDE);
    node_kernel<true ><<< 512, 256, 0, stream>>>(W, bias, out,    out,  85, 2, 4, OUT_STRIDE);
    // lvl5: global-sweep, 512 resident blocks x 16 items (8192 items total)
    sweep_kernel<<<512, 256, 0, stream>>>(W, bias, out, out, 341, 16, 512);
}

// Round 12
// 345.414 us; speedup vs baseline: 1.1082x; 1.1082x over previous
//
#include <hip/hip_runtime.h>
#include <type_traits>

#define D 512
#define NNODES 1365
#define OUT_STRIDE (NNODES * D)   // 698880 floats per batch row

typedef __attribute__((ext_vector_type(4))) float f32x4;
typedef __attribute__((ext_vector_type(8))) short bf16x8;

union U4 { unsigned u[4]; bf16x8 v; };

__device__ __forceinline__ unsigned cvt_pk_bf16(float s0, float s1) {
    unsigned r;
    asm volatile("v_cvt_pk_bf16_f32 %0, %1, %2" : "=v"(r) : "v"(s0), "v"(s1));
    return r;
}

__device__ __forceinline__ void gld_lds16(const void* g, void* l) {
    __builtin_amdgcn_global_load_lds(
        (const __attribute__((address_space(1))) unsigned*)g,
        (__attribute__((address_space(3))) unsigned*)l, 16, 0, 0);
}

template<int N> __device__ __forceinline__ void waitV() {
    asm volatile("s_waitcnt vmcnt(%0)" :: "i"(N) : "memory");
}

// split-bf16 fp32 MFMA emulation: AhBh + AlBh + AhBl (Wl*pl term dropped,
// ~1e-5 relative -> absmax 0.0156 vs 0.08 threshold)
__device__ __forceinline__ void mfma3(bf16x8 ah, bf16x8 al, f32x4 b0, f32x4 b1,
                                      f32x4& acc) {
    U4 bH, bL;
    float xs[8] = {b0[0],b0[1],b0[2],b0[3],b1[0],b1[1],b1[2],b1[3]};
    #pragma unroll
    for (int k = 0; k < 4; ++k) {
        unsigned hh = cvt_pk_bf16(xs[2*k], xs[2*k+1]);
        float f0 = __uint_as_float(hh << 16);
        float f1 = __uint_as_float(hh & 0xFFFF0000u);
        bL.u[k] = cvt_pk_bf16(xs[2*k] - f0, xs[2*k+1] - f1);
        bH.u[k] = hh;
    }
    acc = __builtin_amdgcn_mfma_f32_16x16x32_bf16(ah, bH.v, acc, 0,0,0);
    acc = __builtin_amdgcn_mfma_f32_16x16x32_bf16(al, bH.v, acc, 0,0,0);
    acc = __builtin_amdgcn_mfma_f32_16x16x32_bf16(ah, bL.v, acc, 0,0,0);
}

__device__ __forceinline__ void build_afrags(const float* arow, int m4,
                                             bf16x8* aH, bf16x8* aL) {
    #pragma unroll
    for (int j = 0; j < 16; ++j) {
        const float* p = arow + j * 32 + m4 * 8;
        f32x4 x0 = *(const f32x4*)p;
        f32x4 x1 = *(const f32x4*)(p + 4);
        float xs[8] = {x0[0],x0[1],x0[2],x0[3],x1[0],x1[1],x1[2],x1[3]};
        U4 h, l;
        #pragma unroll
        for (int k = 0; k < 4; ++k) {
            unsigned hh = cvt_pk_bf16(xs[2*k], xs[2*k+1]);
            float f0 = __uint_as_float(hh << 16);
            float f1 = __uint_as_float(hh & 0xFFFF0000u);
            l.u[k] = cvt_pk_bf16(xs[2*k] - f0, xs[2*k+1] - f1);
            h.u[k] = hh;
        }
        aH[j] = h.v; aL[j] = l.v;
    }
}

// Per-wave streaming GEMM (proven R6 structure, 346 us composite).
// Wave w owns 16-row groups; group processed as 4 x 8KB K-quarters,
// double-buffered via global_load_lds with counted vmcnt(8) (tail: 0).
// A operand (pa row per lane) as bf16 hi/lo frags in registers.
template<bool RELU>
__global__ __launch_bounds__(256, 2)
void node_kernel(const float* __restrict__ W, const float* __restrict__ bias,
                 const float* __restrict__ src_base, float* __restrict__ out,
                 int node_start, int bpn, int ngroups, int src_stride)
{
    __shared__ float Wt[4][2][2048];   // 4 waves x 2 bufs x 8 KB
    __shared__ float bias_lds[512];

    const int tid  = threadIdx.x;
    const int w    = tid >> 6;
    const int lane = tid & 63;
    const int m4   = lane >> 4;
    const int c0   = lane & 15;

    const int node  = node_start + blockIdx.x / bpn;
    const int nbase = (blockIdx.x % bpn) * (64 * ngroups);
    const char* Wn  = (const char*)(W + (size_t)node * (D * D));

    for (int t = tid; t < 64 * ngroups; t += 256)
        bias_lds[t] = bias[(size_t)node * D + nbase + t];

    const float* arow = (RELU ? src_base + (size_t)((node - 1) >> 2) * D
                              : src_base) + (size_t)c0 * src_stride;
    bf16x8 aH[16], aL[16];
    build_afrags(arow, m4, aH, aL);
    __syncthreads();

    int loffs[8];
    const int rr  = lane >> 5;
    const int off = (lane & 31) * 16;
    #pragma unroll
    for (int i = 0; i < 8; ++i) {
        const int r = i * 2 + rr;
        loffs[i] = r * 2048 + (off ^ ((r & 7) << 4));
    }
    auto issue = [&](const char* gsrc, int buf) {
        char* ldst = (char*)&Wt[w][buf][0];
        #pragma unroll
        for (int i = 0; i < 8; ++i)
            gld_lds16(gsrc + loffs[i], ldst + i * 1024);
    };

    const int rsw = (c0 & 7) << 4;
    const int po0 = c0 * 512 + ((m4 * 32)      ^ rsw);
    const int po1 = c0 * 512 + ((m4 * 32 + 16) ^ rsw);

    const size_t GRP = (size_t)64 * 2048;
    const char* gcur = Wn + (size_t)(nbase + w * 16) * 2048;
    issue(gcur,       0);
    issue(gcur + 512, 1);

    float* optr = out + (size_t)node * D + nbase + w * 16 + c0;
    const float* blds = &bias_lds[w * 16 + c0];

    auto compute_q = [&](auto qc, f32x4& acc) {
        constexpr int Q = decltype(qc)::value;
        const char* tb = (const char*)&Wt[w][Q & 1][0];
        #pragma unroll
        for (int ks = 0; ks < 4; ++ks) {
            f32x4 b0 = *(const f32x4*)(tb + po0 + ks * 128);
            f32x4 b1 = *(const f32x4*)(tb + po1 + ks * 128);
            mfma3(aH[Q*4+ks], aL[Q*4+ks], b0, b1, acc);
        }
    };

    #pragma clang loop unroll(disable)
    for (int g = 0; g < ngroups; ++g) {
        const bool last = (g == ngroups - 1);
        const char* gnext = gcur + GRP;
        f32x4 acc = {0.f,0.f,0.f,0.f};

        waitV<8>();
        compute_q(std::integral_constant<int,0>{}, acc);
        issue(gcur + 1024, 0);
        waitV<8>();
        compute_q(std::integral_constant<int,1>{}, acc);
        issue(gcur + 1536, 1);
        waitV<8>();
        compute_q(std::integral_constant<int,2>{}, acc);
        if (!last) issue(gnext, 0);
        if (last) waitV<0>(); else waitV<8>();
        compute_q(std::integral_constant<int,3>{}, acc);

        const float bv = *blds;
        #pragma unroll
        for (int i = 0; i < 4; ++i) {
            float v = acc[i] + bv;
            if (RELU) v = fmaxf(v, 0.f);
            optr[(size_t)(m4 * 4 + i) * OUT_STRIDE] = v;
        }
        if (!last) issue(gnext + 512, 1);

        gcur = gnext; optr += 64; blds += 64;
    }
}

extern "C" void kernel_launch(void* const* d_in, const int* in_sizes, int n_in,
                              void* d_out, int out_size, void* d_ws, size_t ws_size,
                              hipStream_t stream) {
    const float* inputs = (const float*)d_in[0];   // (16, 512)
    const float* W      = (const float*)d_in[1];   // (1365, 512, 512)
    const float* bias   = (const float*)d_in[2];   // (1365, 512)
    float* out          = (float*)d_out;           // (16, 1365*512)

    // <RELU> <<<nodes*bpn>>> (node_start, bpn, ngroups, src_stride)
    node_kernel<false><<<   8, 256, 0, stream>>>(W, bias, inputs, out,   0, 8, 1, D);
    node_kernel<true ><<<  32, 256, 0, stream>>>(W, bias, out,    out,   1, 8, 1, OUT_STRIDE);
    node_kernel<true ><<< 128, 256, 0, stream>>>(W, bias, out,    out,   5, 8, 1, OUT_STRIDE);
    node_kernel<true ><<< 512, 256, 0, stream>>>(W, bias, out,    out,  21, 8, 1, OUT_STRIDE);
    node_kernel<true ><<< 512, 256, 0, stream>>>(W, bias, out,    out,  85, 2, 4, OUT_STRIDE);
    node_kernel<true ><<<1024, 256, 0, stream>>>(W, bias, out,    out, 341, 1, 8, OUT_STRIDE);
}